// Round 4
// baseline (1397.936 us; speedup 1.0000x reference)
//
#include <hip/hip_runtime.h>
#include <cstddef>

#define NN   32
#define CIN  256
#define COUT 256
#define TT   128
#define VV   25
#define KK   3
#define TV   (TT*VV)        // 3200
#define NTVC (NN*TT*VV)     // 102400
#define BN_EPS 1e-5f

typedef __attribute__((ext_vector_type(8))) short bf16x8;   // 8 bf16 = 4 VGPRs
typedef __attribute__((ext_vector_type(4))) float f32x4;    // MFMA C/D

__device__ __forceinline__ unsigned short f2bf(float f) {
    unsigned int u = __float_as_uint(f);
    u = (u + 0x7fffu + ((u >> 16) & 1u)) >> 16;   // RNE
    return (unsigned short)u;
}
__device__ __forceinline__ float bf2f(unsigned short h) {
    return __uint_as_float(((unsigned int)h) << 16);
}

// ---------------- K0: W fp32 -> bf16 ----------------
__global__ __launch_bounds__(256)
void convert_w_kernel(const float* __restrict__ W, unsigned short* __restrict__ Wb) {
    int i = blockIdx.x * 256 + threadIdx.x;   // 768 blocks, exact
    Wb[i] = f2bf(W[i]);
}

// ---------------- K1: x [n][c][tv] fp32 -> xT [n][tv][c] bf16 ----------------
__global__ __launch_bounds__(256)
void transpose_x_kernel(const float* __restrict__ x, unsigned short* __restrict__ xT) {
    __shared__ float T[64][65];
    const int n   = blockIdx.z;
    const int s0  = blockIdx.x * 64;   // 50 tiles
    const int c0  = blockIdx.y * 64;   // 4 tiles
    const int tid = threadIdx.x;
    const int r    = tid >> 4;         // 0..15
    const int col4 = (tid & 15) * 4;

    const float* xp = x + (size_t)(n * CIN + c0) * TV + s0;
    for (int rr = r; rr < 64; rr += 16) {
        float4 v = *(const float4*)(xp + (size_t)rr * TV + col4);
        T[rr][col4 + 0] = v.x; T[rr][col4 + 1] = v.y;
        T[rr][col4 + 2] = v.z; T[rr][col4 + 3] = v.w;
    }
    __syncthreads();
    unsigned short* op = xT + ((size_t)n * TV + s0) * CIN + c0;
    for (int ss = r; ss < 64; ss += 16) {
        ushort4 o;
        o.x = f2bf(T[col4 + 0][ss]);
        o.y = f2bf(T[col4 + 1][ss]);
        o.z = f2bf(T[col4 + 2][ss]);
        o.w = f2bf(T[col4 + 3][ss]);
        *(ushort4*)(op + (size_t)ss * CIN + col4) = o;
    }
}

// ---------------- K2: MFMA conv GEMM + MFMA adjacency ----------------
// block = (n, t-pair), 512 threads = 8 waves.
// Stage A: wave wg owns o in [96wg, 96wg+96) x s-tiles {0,16,32,34},
//   K-loop software-pipelined 1 deep.
// Stage B: 4 passes (t' x c-half); yT[128][96] bf16 holds one (t',half);
//   element (row,col) stores v = col ^ ((row>>2)&3)*8 (XOR swizzle).
//   out[c][w] = sum_kv yT * Ab via 16x16x32 MFMA, Ab zero-padded.
// Output: results held in regs, staged to LDS OutB[256][50] bf16, then one
//   contiguous 25.6 KB block copy into y2 slice (which aliases this block's
//   own consumed xT slice).
__global__ __launch_bounds__(512, 6)
void gemm_adj_kernel(const unsigned short* __restrict__ xT,
                     const unsigned short* __restrict__ Wb,
                     const float* __restrict__ A,
                     const float* __restrict__ b,
                     unsigned short* __restrict__ y2)
{
    __shared__ __align__(16) char smem[30720];
    unsigned short* yT = (unsigned short*)smem;            // [128][96] = 24576 B
    unsigned short* Ab = (unsigned short*)(smem + 24576);  // [32][96]  =  6144 B

    const int tid  = threadIdx.x;
    const int lane = tid & 63;
    const int wg   = tid >> 6;      // wave 0..7
    const int ln15 = lane & 15;
    const int quad = lane >> 4;     // 0..3
    const int tp   = blockIdx.x & 63;
    const int n    = blockIdx.x >> 6;
    const int t0   = tp * 2;

    // Ab[w][kv] = A[k][v][w], zero-padded
    for (int i = tid; i < 32 * 96; i += 512) {
        int w  = i / 96;
        int kv = i - w * 96;
        int k  = kv >> 5;
        int v  = kv & 31;
        float val = (v < VV && w < VV) ? A[k * VV * VV + v * VV + w] : 0.f;
        Ab[i] = f2bf(val);
    }
    // zero v-pad slots of yT once (valid-v writes never touch them)
    for (int i = tid; i < 128 * 21; i += 512) {
        int rr = i / 21;
        int r2 = i - rr * 21;
        int k  = r2 / 7;
        int v  = VV + (r2 - k * 7);
        yT[rr * 96 + k * 32 + (v ^ (((rr >> 2) & 3) << 3))] = 0;
    }

    const int soff[4] = {0, 16, 32, 34};

    // ---- Stage A: conv GEMM, bias in acc init, 1-deep pipelined K ----
    f32x4 acc[6][4];
    {
        const int ob = 96 * wg + 4 * quad;
        #pragma unroll
        for (int mt = 0; mt < 6; ++mt) {
            float4 bv = *(const float4*)(b + ob + 16 * mt);
            #pragma unroll
            for (int nt = 0; nt < 4; ++nt) {
                acc[mt][nt][0] = bv.x; acc[mt][nt][1] = bv.y;
                acc[mt][nt][2] = bv.z; acc[mt][nt][3] = bv.w;
            }
        }
    }
    const unsigned short* wp = Wb + (size_t)(96 * wg + ln15) * CIN + quad * 8;
    const unsigned short* xp = xT + ((size_t)n * TV + t0 * VV + ln15) * CIN + quad * 8;

    bf16x8 bcur[4], acur[6], bnxt[4], anxt[6];
    #pragma unroll
    for (int nt = 0; nt < 4; ++nt)
        bcur[nt] = *(const bf16x8*)(xp + (size_t)soff[nt] * CIN);
    #pragma unroll
    for (int mt = 0; mt < 6; ++mt)
        acur[mt] = *(const bf16x8*)(wp + (size_t)(mt * 16) * CIN);

    #pragma unroll
    for (int ks = 0; ks < 8; ++ks) {
        if (ks < 7) {
            #pragma unroll
            for (int nt = 0; nt < 4; ++nt)
                bnxt[nt] = *(const bf16x8*)(xp + (size_t)soff[nt] * CIN + (ks + 1) * 32);
            #pragma unroll
            for (int mt = 0; mt < 6; ++mt)
                anxt[mt] = *(const bf16x8*)(wp + (size_t)(mt * 16) * CIN + (ks + 1) * 32);
        }
        #pragma unroll
        for (int mt = 0; mt < 6; ++mt)
            #pragma unroll
            for (int nt = 0; nt < 4; ++nt)
                acc[mt][nt] = __builtin_amdgcn_mfma_f32_16x16x32_bf16(
                                  acur[mt], bcur[nt], acc[mt][nt], 0, 0, 0);
        if (ks < 7) {
            #pragma unroll
            for (int nt = 0; nt < 4; ++nt) bcur[nt] = bnxt[nt];
            #pragma unroll
            for (int mt = 0; mt < 6; ++mt) acur[mt] = anxt[mt];
        }
    }

    // ---- Stage B: 4 passes (t' x c-half) ----
    float out_f[2][2][2][4];
    bf16x8 bq[3][2];
    const int rswz = ((quad ^ (ln15 >> 2)) & 3) << 3;

    #pragma unroll
    for (int tp1 = 0; tp1 < 2; ++tp1) {
        #pragma unroll
        for (int ch = 0; ch < 2; ++ch) {
            __syncthreads();   // prev pass reads done / init visible
            auto wr = [&](int nt, int v, bool pred) {
                if (pred) {
                    int slot = v ^ (quad << 3);
                    #pragma unroll
                    for (int mt = 0; mt < 6; ++mt) {
                        int o  = 96 * wg + 16 * mt;
                        int k  = o >> 8;
                        int oc = o & 255;
                        if (((oc >> 7) & 1) == ch) {
                            int base = ((oc & 127) + 4 * quad) * 96 + k * 32 + slot;
                            #pragma unroll
                            for (int r = 0; r < 4; ++r)
                                yT[base + r * 96] = f2bf(acc[mt][nt][r]);
                        }
                    }
                }
            };
            if (tp1 == 0) {
                wr(0, ln15, true);
                wr(1, 16 + ln15, ln15 < 9);
            } else {
                wr(1, ln15 - 9, ln15 >= 9);
                wr(2, 7 + ln15, true);
                wr(3, 9 + ln15, true);
            }
            __syncthreads();

            if (tp1 == 0 && ch == 0) {
                #pragma unroll
                for (int k = 0; k < 3; ++k)
                    #pragma unroll
                    for (int nw = 0; nw < 2; ++nw)
                        bq[k][nw] = *(const bf16x8*)&Ab[(16 * nw + ln15) * 96 + k * 32 + quad * 8];
            }

            f32x4 a2[2];
            #pragma unroll
            for (int nw = 0; nw < 2; ++nw)
                #pragma unroll
                for (int r = 0; r < 4; ++r) a2[nw][r] = 0.f;
            #pragma unroll
            for (int k = 0; k < 3; ++k) {
                bf16x8 af = *(const bf16x8*)&yT[(wg * 16 + ln15) * 96 + k * 32 + rswz];
                a2[0] = __builtin_amdgcn_mfma_f32_16x16x32_bf16(af, bq[k][0], a2[0], 0, 0, 0);
                a2[1] = __builtin_amdgcn_mfma_f32_16x16x32_bf16(af, bq[k][1], a2[1], 0, 0, 0);
            }
            #pragma unroll
            for (int nw = 0; nw < 2; ++nw)
                #pragma unroll
                for (int r = 0; r < 4; ++r) out_f[tp1][ch][nw][r] = a2[nw][r];
        }
    }

    // ---- stage output to LDS (aliases yT/Ab, both dead now) ----
    __syncthreads();
    unsigned short* OutB = (unsigned short*)smem;   // [256][50] = 25600 B
    #pragma unroll
    for (int tp1 = 0; tp1 < 2; ++tp1)
        #pragma unroll
        for (int ch = 0; ch < 2; ++ch)
            #pragma unroll
            for (int nw = 0; nw < 2; ++nw)
                if (nw == 0 || ln15 < 9) {
                    int w = nw * 16 + ln15;
                    #pragma unroll
                    for (int r = 0; r < 4; ++r)
                        OutB[(ch * 128 + wg * 16 + 4 * quad + r) * 50 + tp1 * VV + w] =
                            f2bf(out_f[tp1][ch][nw][r]);
                }
    __syncthreads();

    // contiguous 25.6 KB copy into y2 slice (= this block's consumed xT slice)
    const uint4* sB = (const uint4*)OutB;
    uint4* dB = (uint4*)(y2 + (size_t)(n * 64 + tp) * 12800);
    for (int i = tid; i < 1600; i += 512) dB[i] = sB[i];
}

// ---------------- K3: per-channel sum/sumsq over bf16 y2 ----------------
// y2 layout: [n*64+tp][c][50] bf16
__global__ __launch_bounds__(256)
void bn_reduce_kernel(const unsigned short* __restrict__ y2, float* __restrict__ stats)
{
    const int c = blockIdx.x;
    const int n = blockIdx.y;
    const unsigned int* base = (const unsigned int*)y2 + (size_t)n * 64 * 6400 + c * 25;
    float s1 = 0.f, s2 = 0.f;
    for (int i = threadIdx.x; i < 1600; i += 256) {
        int tp = i / 25, j = i - tp * 25;
        unsigned int u = base[(size_t)tp * 6400 + j];
        float lo = bf2f((unsigned short)(u & 0xffffu));
        float hi = bf2f((unsigned short)(u >> 16));
        s1 += lo + hi;
        s2 += lo * lo + hi * hi;
    }
    #pragma unroll
    for (int off = 32; off; off >>= 1) {
        s1 += __shfl_down(s1, off);
        s2 += __shfl_down(s2, off);
    }
    if ((threadIdx.x & 63) == 0) {
        atomicAdd(&stats[c], s1);
        atomicAdd(&stats[COUT + c], s2);
    }
}

// ---------------- K4: stats -> scale/shift ----------------
__global__ void bn_stats_kernel(const float* __restrict__ stats,
                                const float* __restrict__ gamma,
                                const float* __restrict__ beta,
                                float* __restrict__ ss)
{
    int c = threadIdx.x;
    float mu  = stats[c] * (1.f / NTVC);
    float var = stats[COUT + c] * (1.f / NTVC) - mu * mu;
    float sc  = gamma[c] * rsqrtf(var + BN_EPS);
    ss[c]        = sc;
    ss[COUT + c] = beta[c] - mu * sc;
}

// ---------------- K5: normalize + ReLU, bf16 y2 -> fp32 out ----------------
__global__ __launch_bounds__(256)
void bn_apply_kernel(const unsigned short* __restrict__ y2,
                     const float* __restrict__ ss,
                     float* __restrict__ out)
{
    int w = blockIdx.x * 256 + threadIdx.x;    // dword idx over 13107200
    int rest = w / 25;
    int p2   = w - rest * 25;
    int c    = rest & 255;
    int nt   = rest >> 8;                      // n*64 + tp
    unsigned int u = ((const unsigned int*)y2)[w];
    float sc = ss[c], sh = ss[COUT + c];
    float lo = fmaxf(bf2f((unsigned short)(u & 0xffffu)) * sc + sh, 0.f);
    float hi = fmaxf(bf2f((unsigned short)(u >> 16)) * sc + sh, 0.f);
    int tp = nt & 63, n = nt >> 6;
    float2 o2 = make_float2(lo, hi);
    ((float2*)out)[(size_t)(n * COUT + c) * 1600 + tp * 25 + p2] = o2;
}

extern "C" void kernel_launch(void* const* d_in, const int* in_sizes, int n_in,
                              void* d_out, int out_size, void* d_ws, size_t ws_size,
                              hipStream_t stream)
{
    const float* x     = (const float*)d_in[0];
    const float* A     = (const float*)d_in[1];
    const float* W     = (const float*)d_in[2];
    const float* b     = (const float*)d_in[3];
    const float* gamma = (const float*)d_in[4];
    const float* beta  = (const float*)d_in[5];
    float* out = (float*)d_out;

    // ws: [0,2048) stats  [2048,4096) scale/shift  [4096,+384K) W bf16
    //     [397312, +52.4MB) xT bf16  (y2 bf16 aliases xT slice-for-slice)
    float* stats = (float*)d_ws;
    float* ss    = stats + 512;
    unsigned short* Wb  = (unsigned short*)((char*)d_ws + 4096);
    unsigned short* xTb = (unsigned short*)((char*)d_ws + 4096 + (size_t)KK * COUT * CIN * 2);
    unsigned short* y2b = xTb;   // alias, see gemm_adj_kernel

    hipMemsetAsync(stats, 0, 2 * COUT * sizeof(float), stream);

    convert_w_kernel<<<(KK * COUT * CIN) / 256, 256, 0, stream>>>(W, Wb);
    transpose_x_kernel<<<dim3(TV / 64, CIN / 64, NN), 256, 0, stream>>>(x, xTb);
    gemm_adj_kernel<<<NN * (TT / 2), 512, 0, stream>>>(xTb, Wb, A, b, y2b);
    bn_reduce_kernel<<<dim3(COUT, NN), 256, 0, stream>>>(y2b, stats);
    bn_stats_kernel<<<1, 256, 0, stream>>>(stats, gamma, beta, ss);
    bn_apply_kernel<<<(NN * COUT * TT * VV) / (2 * 256), 256, 0, stream>>>(y2b, ss, out);
}